// Round 4
// baseline (1390.471 us; speedup 1.0000x reference)
//
#include <hip/hip_runtime.h>

// LSTM T=256, B=128, D=512, H=512 — round 4: poll-on-data (epoch-tagged h pairs).
//   grid = 256 blocks (8 row-groups x 32 col-blocks), 256 threads (4 waves).
//   Block tile: 16 batch rows x 16 hidden units (all 4 gates).
//   Waves K-split: wave w owns k in [w*128,(w+1)*128) of x-half AND h-half.
//   W fragments (4 gates x 8 chunks = 128 regs) preloaded ONCE (unified VGPR/AGPR).
//   Sync: NO flags, NO counters, NO barriers around h exchange. h is published
//   as u32 pairs {h_bf16 << 16 | epoch} via relaxed agent-scope stores; each
//   consumer wave polls the exact 32 pairs it needs until all tags == t, at
//   which point the h data is already in registers (flag fused with data:
//   2 LLC hops/step instead of 4). Parity double-buffer makes overwrite safe.

#define TT 256
#define BB 128
#define DD 512
#define HH 512
#define KK 1024
#define NBLK 256

typedef __bf16 bf16x8 __attribute__((ext_vector_type(8)));
typedef float f32x4 __attribute__((ext_vector_type(4)));
typedef unsigned short u16x8 __attribute__((ext_vector_type(8)));

__device__ __forceinline__ unsigned short f2bf(float f) {
  unsigned b = __builtin_bit_cast(unsigned, f);
  return (unsigned short)((b + 0x7fffu + ((b >> 16) & 1u)) >> 16);
}
__device__ __forceinline__ float fexp(float x) {
  return __builtin_amdgcn_exp2f(x * 1.4426950408889634f);
}
__device__ __forceinline__ float fsig(float x) {
  return __builtin_amdgcn_rcpf(1.0f + fexp(-x));
}
__device__ __forceinline__ float ftanh(float x) {
  return 2.0f * fsig(2.0f * x) - 1.0f;
}

// ---- prep: X fp32 -> bf16 (RNE), 8 elems/thread ----
__global__ __launch_bounds__(256) void convert_x_kernel(const float* __restrict__ X,
                                                        unsigned short* __restrict__ Xbf) {
  size_t i = (size_t)blockIdx.x * 256 + threadIdx.x;
  const float4* src = (const float4*)X + i * 2;
  float4 v0 = src[0], v1 = src[1];
  u16x8 o;
  o[0] = f2bf(v0.x); o[1] = f2bf(v0.y); o[2] = f2bf(v0.z); o[3] = f2bf(v0.w);
  o[4] = f2bf(v1.x); o[5] = f2bf(v1.y); o[6] = f2bf(v1.z); o[7] = f2bf(v1.w);
  ((u16x8*)Xbf)[i] = o;
}

// ---- prep: build WT[g][k] bf16, g = q*512 + j; k<512 from Wq_x[k][j], else Wq_h[k-512][j].
__global__ __launch_bounds__(256) void build_wt_kernel(
    const float* __restrict__ Wax, const float* __restrict__ Wix,
    const float* __restrict__ Wfx, const float* __restrict__ Wox,
    const float* __restrict__ Wah, const float* __restrict__ Wih,
    const float* __restrict__ Wfh, const float* __restrict__ Woh,
    unsigned short* __restrict__ WT) {
  __shared__ float tile[64][65];
  int bid = blockIdx.x;           // q*128 + jt*16 + kt
  int q  = bid >> 7;
  int jt = (bid >> 4) & 7;
  int kt = bid & 15;
  const float* Wx[4] = {Wax, Wix, Wfx, Wox};
  const float* Wh[4] = {Wah, Wih, Wfh, Woh};
  const float* src = (kt < 8) ? Wx[q] : Wh[q];
  int k0 = (kt & 7) * 64;
  int j0 = jt * 64;
  int tid = threadIdx.x;
#pragma unroll
  for (int e = 0; e < 16; ++e) {
    int lin = e * 256 + tid;
    int kk = lin >> 6, jj = lin & 63;
    tile[kk][jj] = src[(size_t)(k0 + kk) * HH + j0 + jj];
  }
  __syncthreads();
#pragma unroll
  for (int e = 0; e < 16; ++e) {
    int lin = e * 256 + tid;
    int jj = lin >> 6, kk = lin & 63;
    WT[(size_t)(q * HH + j0 + jj) * KK + kt * 64 + kk] = f2bf(tile[kk][jj]);
  }
}

// ---- main persistent recurrence kernel ----
__global__ __launch_bounds__(256, 1) void lstm_main(
    const unsigned short* __restrict__ Xbf,
    const unsigned short* __restrict__ WT,
    const float* __restrict__ ba, const float* __restrict__ bi,
    const float* __restrict__ bfg, const float* __restrict__ bo,
    unsigned* __restrict__ hpair,      // [2][BB][HH] u32: {h_bf16:16 | epoch:16}
    float* __restrict__ out) {
  const int tid  = threadIdx.x;
  const int bid  = blockIdx.x;
  const int lane = tid & 63;
  const int wave = tid >> 6;
  const int rb = bid >> 5;            // 0..7  (16 batch rows) — recurrence group
  const int cb = bid & 31;            // 0..31 (16 hidden units)
  const int l15 = lane & 15;
  const int lk8 = (lane >> 4) * 8;    // k offset within a 32-chunk
  const int rbase = rb * 16;
  const int colg = cb * 16 + l15;     // hidden index for B-fragments
  const int wk = wave * 128;          // this wave's K-slice base (within each half)

  // ---- preload W fragments (constant across all timesteps) ----
  bf16x8 wf[4][8];
#pragma unroll
  for (int g = 0; g < 4; ++g) {
    const unsigned short* wg = WT + (size_t)(g * HH + colg) * KK + lk8;
#pragma unroll
    for (int c = 0; c < 8; ++c) {
      int kb = (c < 4) ? (wk + c * 32) : (DD + wk + (c - 4) * 32);
      wf[g][c] = *(const bf16x8*)(wg + kb);
    }
  }

  // per-thread output element (reduce phase): row = tid>>4, col = tid&15
  const int el_row = tid >> 4;
  const int el_col = tid & 15;
  const int el_colg = cb * 16 + el_col;
  const int el_rowg = rbase + el_row;
  const float b0 = ba[el_colg], b1 = bi[el_colg], b2 = bfg[el_colg], b3 = bo[el_colg];
  const int lsrc = (el_row >> 2) * 16 + el_col;  // source lane in C-fragment
  const int rsrc = el_row & 3;                   // source reg in C-fragment

  const unsigned short* xbase = Xbf + (size_t)(rbase + l15) * DD + wk + lk8;
  const size_t hrowp = (size_t)(rbase + l15) * HH + wk + lk8;  // u32 index into hpair plane
  const size_t hstore_el = (size_t)el_rowg * HH + el_colg;     // u32 index for publish

  __shared__ f32x4 part[2][4][4][64];   // [buf][wave][gate][lane]

  float s_c = 0.f;   // cell state for this thread's element

  for (int t = 0; t < TT; ++t) {
    // ---- x-projection part (no cross-block dependency) ----
    const unsigned short* xt = xbase + (size_t)t * BB * DD;
    bf16x8 ax0 = *(const bf16x8*)(xt);
    bf16x8 ax1 = *(const bf16x8*)(xt + 32);
    bf16x8 ax2 = *(const bf16x8*)(xt + 64);
    bf16x8 ax3 = *(const bf16x8*)(xt + 96);

    f32x4 acc[4];
#pragma unroll
    for (int g = 0; g < 4; ++g) {
      f32x4 z = {0.f, 0.f, 0.f, 0.f};
      acc[g] = __builtin_amdgcn_mfma_f32_16x16x32_bf16(ax0, wf[g][0], z, 0, 0, 0);
      acc[g] = __builtin_amdgcn_mfma_f32_16x16x32_bf16(ax1, wf[g][1], acc[g], 0, 0, 0);
      acc[g] = __builtin_amdgcn_mfma_f32_16x16x32_bf16(ax2, wf[g][2], acc[g], 0, 0, 0);
      acc[g] = __builtin_amdgcn_mfma_f32_16x16x32_bf16(ax3, wf[g][3], acc[g], 0, 0, 0);
    }

    // ---- h part: poll directly on epoch-tagged data (tag == t), then MFMA ----
    if (t > 0) {
      const unsigned tagw = (unsigned)t;
      const unsigned* hp = hpair + (size_t)((t & 1) ^ 1) * BB * HH + hrowp;
      unsigned q[4][8];
      while (true) {
#pragma unroll
        for (int c = 0; c < 4; ++c)
#pragma unroll
          for (int j = 0; j < 8; ++j)
            q[c][j] = __hip_atomic_load(hp + c * 32 + j, __ATOMIC_RELAXED,
                                        __HIP_MEMORY_SCOPE_AGENT);
        unsigned bad = 0;
#pragma unroll
        for (int c = 0; c < 4; ++c)
#pragma unroll
          for (int j = 0; j < 8; ++j)
            bad |= (q[c][j] ^ tagw);
        if (__all((bad & 0xffffu) == 0u)) break;
        __builtin_amdgcn_s_sleep(1);
      }
      // unpack {h:16|tag:16} pairs -> bf16x8 fragments (h in high 16 bits)
      bf16x8 hf[4];
#pragma unroll
      for (int c = 0; c < 4; ++c) {
        unsigned w0 = (q[c][0] >> 16) | (q[c][1] & 0xffff0000u);
        unsigned w1 = (q[c][2] >> 16) | (q[c][3] & 0xffff0000u);
        unsigned w2 = (q[c][4] >> 16) | (q[c][5] & 0xffff0000u);
        unsigned w3 = (q[c][6] >> 16) | (q[c][7] & 0xffff0000u);
        uint4 u = make_uint4(w0, w1, w2, w3);
        hf[c] = __builtin_bit_cast(bf16x8, u);
      }
#pragma unroll
      for (int g = 0; g < 4; ++g) {
        acc[g] = __builtin_amdgcn_mfma_f32_16x16x32_bf16(hf[0], wf[g][4], acc[g], 0, 0, 0);
        acc[g] = __builtin_amdgcn_mfma_f32_16x16x32_bf16(hf[1], wf[g][5], acc[g], 0, 0, 0);
        acc[g] = __builtin_amdgcn_mfma_f32_16x16x32_bf16(hf[2], wf[g][6], acc[g], 0, 0, 0);
        acc[g] = __builtin_amdgcn_mfma_f32_16x16x32_bf16(hf[3], wf[g][7], acc[g], 0, 0, 0);
      }
    }

    // ---- write K-partials to LDS (parity buffer; one barrier per step) ----
    const int pb = t & 1;
#pragma unroll
    for (int g = 0; g < 4; ++g) part[pb][wave][g][lane] = acc[g];
    __syncthreads();

    // ---- per-thread reduce over 4 waves + gate nonlinearity ----
    float g0 = b0, g1 = b1, g2 = b2, g3 = b3;
#pragma unroll
    for (int w = 0; w < 4; ++w) {
      g0 += ((const float*)&part[pb][w][0][lsrc])[rsrc];
      g1 += ((const float*)&part[pb][w][1][lsrc])[rsrc];
      g2 += ((const float*)&part[pb][w][2][lsrc])[rsrc];
      g3 += ((const float*)&part[pb][w][3][lsrc])[rsrc];
    }
    float av = ftanh(g0);
    float iv = fsig(g1);
    float fv = fsig(g2);
    float ov = fsig(g3);
    s_c = av * iv + s_c * fv;
    float hv = ftanh(s_c) * ov;

    // ---- publish h_t as {h:16|epoch=t+1:16} — fire-and-forget, on critical path first ----
    if (t < TT - 1) {
      unsigned pairv = (unsigned)(t + 1) | ((unsigned)f2bf(hv) << 16);
      __hip_atomic_store(&hpair[(size_t)pb * BB * HH + hstore_el], pairv,
                         __ATOMIC_RELAXED, __HIP_MEMORY_SCOPE_AGENT);
    }

    out[(size_t)t * BB * HH + hstore_el] = hv;
  }
}

extern "C" void kernel_launch(void* const* d_in, const int* in_sizes, int n_in,
                              void* d_out, int out_size, void* d_ws, size_t ws_size,
                              hipStream_t stream) {
  const float* X   = (const float*)d_in[0];
  const float* Wax = (const float*)d_in[1];
  const float* Wix = (const float*)d_in[2];
  const float* Wfx = (const float*)d_in[3];
  const float* Wox = (const float*)d_in[4];
  const float* Wah = (const float*)d_in[5];
  const float* Wih = (const float*)d_in[6];
  const float* Wfh = (const float*)d_in[7];
  const float* Woh = (const float*)d_in[8];
  const float* ba  = (const float*)d_in[9];
  const float* bi  = (const float*)d_in[10];
  const float* bf  = (const float*)d_in[11];
  const float* bo  = (const float*)d_in[12];
  float* out = (float*)d_out;

  char* ws = (char*)d_ws;
  unsigned short* Xbf = (unsigned short*)ws;                       // 33,554,432 B
  unsigned short* WT  = (unsigned short*)(ws + 33554432);          //  4,194,304 B
  unsigned* hpair     = (unsigned*)(ws + 33554432 + 4194304);      //    524,288 B

  // clear epoch tags every launch (replay safety: stale tags would alias)
  hipMemsetAsync(hpair, 0, 524288, stream);

  convert_x_kernel<<<8192, 256, 0, stream>>>(X, Xbf);
  build_wt_kernel<<<512, 256, 0, stream>>>(Wax, Wix, Wfx, Wox, Wah, Wih, Wfh, Woh, WT);
  lstm_main<<<NBLK, 256, 0, stream>>>(Xbf, WT, ba, bi, bf, bo, hpair, out);
}

// Round 5
// 830.574 us; speedup vs baseline: 1.6741x; 1.6741x over previous
//
#include <hip/hip_runtime.h>

// LSTM T=256, B=128, D=512, H=512 — round 5: round-3 skeleton + de-serialized sync.
//   grid = 256 blocks (8 row-groups x 32 col-blocks), 256 threads (4 waves).
//   Block tile: 16 batch rows x 16 hidden units (all 4 gates).
//   Waves K-split: wave w owns k in [w*128,(w+1)*128) of x-half AND h-half.
//   W fragments (4 gates x 8 chunks = 128 regs) preloaded ONCE (unified VGPR/AGPR).
//   Sync per step (group rb = 32 blocks):
//     producer: reduce-sync (__syncthreads drains all waves' sc1 h-stores via
//               compiler vmcnt(0)) -> tid0 plain relaxed sc1 store to its own
//               128B-padded flag line (NO atomicAdd serialization).
//     consumer: EACH wave polls the 32 flag lines in parallel (lanes 0..31,
//               one load each + __any ballot) -> h loads start per-wave, no
//               post-poll barrier.
//     out-store issued AFTER flag publish (off the pre-flag drain path).
//   t=0 skips h-part (h_{-1}=0) -> only flags (32KB) memset per launch.

#define TT 256
#define BB 128
#define DD 512
#define HH 512
#define KK 1024
#define NBLK 256

typedef __bf16 bf16x8 __attribute__((ext_vector_type(8)));
typedef float f32x4 __attribute__((ext_vector_type(4)));
typedef unsigned short u16x8 __attribute__((ext_vector_type(8)));
typedef unsigned long long u64;

union h128 { u64 q[2]; bf16x8 v; };

__device__ __forceinline__ unsigned short f2bf(float f) {
  unsigned b = __builtin_bit_cast(unsigned, f);
  return (unsigned short)((b + 0x7fffu + ((b >> 16) & 1u)) >> 16);
}
__device__ __forceinline__ float fexp(float x) {
  return __builtin_amdgcn_exp2f(x * 1.4426950408889634f);
}
__device__ __forceinline__ float fsig(float x) {
  return __builtin_amdgcn_rcpf(1.0f + fexp(-x));
}
__device__ __forceinline__ float ftanh(float x) {
  return 2.0f * fsig(2.0f * x) - 1.0f;
}

// ---- prep: X fp32 -> bf16 (RNE), 8 elems/thread ----
__global__ __launch_bounds__(256) void convert_x_kernel(const float* __restrict__ X,
                                                        unsigned short* __restrict__ Xbf) {
  size_t i = (size_t)blockIdx.x * 256 + threadIdx.x;
  const float4* src = (const float4*)X + i * 2;
  float4 v0 = src[0], v1 = src[1];
  u16x8 o;
  o[0] = f2bf(v0.x); o[1] = f2bf(v0.y); o[2] = f2bf(v0.z); o[3] = f2bf(v0.w);
  o[4] = f2bf(v1.x); o[5] = f2bf(v1.y); o[6] = f2bf(v1.z); o[7] = f2bf(v1.w);
  ((u16x8*)Xbf)[i] = o;
}

// ---- prep: build WT[g][k] bf16, g = q*512 + j; k<512 from Wq_x[k][j], else Wq_h[k-512][j].
__global__ __launch_bounds__(256) void build_wt_kernel(
    const float* __restrict__ Wax, const float* __restrict__ Wix,
    const float* __restrict__ Wfx, const float* __restrict__ Wox,
    const float* __restrict__ Wah, const float* __restrict__ Wih,
    const float* __restrict__ Wfh, const float* __restrict__ Woh,
    unsigned short* __restrict__ WT) {
  __shared__ float tile[64][65];
  int bid = blockIdx.x;           // q*128 + jt*16 + kt
  int q  = bid >> 7;
  int jt = (bid >> 4) & 7;
  int kt = bid & 15;
  const float* Wx[4] = {Wax, Wix, Wfx, Wox};
  const float* Wh[4] = {Wah, Wih, Wfh, Woh};
  const float* src = (kt < 8) ? Wx[q] : Wh[q];
  int k0 = (kt & 7) * 64;
  int j0 = jt * 64;
  int tid = threadIdx.x;
#pragma unroll
  for (int e = 0; e < 16; ++e) {
    int lin = e * 256 + tid;
    int kk = lin >> 6, jj = lin & 63;
    tile[kk][jj] = src[(size_t)(k0 + kk) * HH + j0 + jj];
  }
  __syncthreads();
#pragma unroll
  for (int e = 0; e < 16; ++e) {
    int lin = e * 256 + tid;
    int jj = lin >> 6, kk = lin & 63;
    WT[(size_t)(q * HH + j0 + jj) * KK + kt * 64 + kk] = f2bf(tile[kk][jj]);
  }
}

// ---- main persistent recurrence kernel ----
__global__ __launch_bounds__(256, 1) void lstm_main(
    const unsigned short* __restrict__ Xbf,
    const unsigned short* __restrict__ WT,
    const float* __restrict__ ba, const float* __restrict__ bi,
    const float* __restrict__ bfg, const float* __restrict__ bo,
    unsigned short* __restrict__ hbuf,
    float* __restrict__ out,
    unsigned* __restrict__ flags) {     // [8 groups][32 blocks] x 128B-padded lines
  const int tid  = threadIdx.x;
  const int bid  = blockIdx.x;
  const int lane = tid & 63;
  const int wave = tid >> 6;
  const int rb = bid >> 5;            // 0..7  (16 batch rows) — recurrence group
  const int cb = bid & 31;            // 0..31 (16 hidden units)
  const int l15 = lane & 15;
  const int lk8 = (lane >> 4) * 8;    // k offset within a 32-chunk
  const int rbase = rb * 16;
  const int colg = cb * 16 + l15;     // hidden index for B-fragments
  const int wk = wave * 128;          // this wave's K-slice base (within each half)

  // ---- preload W fragments (constant across all timesteps) ----
  bf16x8 wf[4][8];
#pragma unroll
  for (int g = 0; g < 4; ++g) {
    const unsigned short* wg = WT + (size_t)(g * HH + colg) * KK + lk8;
#pragma unroll
    for (int c = 0; c < 8; ++c) {
      int kb = (c < 4) ? (wk + c * 32) : (DD + wk + (c - 4) * 32);
      wf[g][c] = *(const bf16x8*)(wg + kb);
    }
  }

  // per-thread output element (reduce phase): row = tid>>4, col = tid&15
  const int el_row = tid >> 4;
  const int el_col = tid & 15;
  const int el_colg = cb * 16 + el_col;
  const int el_rowg = rbase + el_row;
  const float b0 = ba[el_colg], b1 = bi[el_colg], b2 = bfg[el_colg], b3 = bo[el_colg];
  const int lsrc = (el_row >> 2) * 16 + el_col;  // source lane in C-fragment
  const int rsrc = el_row & 3;                   // source reg in C-fragment

  const unsigned short* xbase = Xbf + (size_t)(rbase + l15) * DD + wk + lk8;
  const size_t hrow = (size_t)(rbase + l15) * HH + wk + lk8;   // element offset
  const size_t hstore_el = (size_t)el_rowg * HH + el_colg;     // element offset

  // flag slots: flags[(rb*32+cb)*32], 32 u32 (=128B) pad per block
  unsigned* myflag = flags + (size_t)(rb * 32 + cb) * 32;
  const unsigned* pollflag = flags + (size_t)(rb * 32 + (lane & 31)) * 32;

  __shared__ f32x4 part[2][4][4][64];   // [buf][wave][gate][lane]

  float s_c = 0.f;   // cell state for this thread's element

  for (int t = 0; t < TT; ++t) {
    // ---- x-projection part (no cross-block dependency) ----
    const unsigned short* xt = xbase + (size_t)t * BB * DD;
    bf16x8 ax0 = *(const bf16x8*)(xt);
    bf16x8 ax1 = *(const bf16x8*)(xt + 32);
    bf16x8 ax2 = *(const bf16x8*)(xt + 64);
    bf16x8 ax3 = *(const bf16x8*)(xt + 96);

    f32x4 acc[4];
#pragma unroll
    for (int g = 0; g < 4; ++g) {
      f32x4 z = {0.f, 0.f, 0.f, 0.f};
      acc[g] = __builtin_amdgcn_mfma_f32_16x16x32_bf16(ax0, wf[g][0], z, 0, 0, 0);
      acc[g] = __builtin_amdgcn_mfma_f32_16x16x32_bf16(ax1, wf[g][1], acc[g], 0, 0, 0);
      acc[g] = __builtin_amdgcn_mfma_f32_16x16x32_bf16(ax2, wf[g][2], acc[g], 0, 0, 0);
      acc[g] = __builtin_amdgcn_mfma_f32_16x16x32_bf16(ax3, wf[g][3], acc[g], 0, 0, 0);
    }

    if (t > 0) {
      // ---- per-wave parallel poll: lanes 0..31 each watch one block's flag ----
      unsigned v = (unsigned)t;   // lanes >= 32 auto-satisfied
      if (lane < 32)
        v = __hip_atomic_load(pollflag, __ATOMIC_RELAXED, __HIP_MEMORY_SCOPE_AGENT);
      while (__any((int)v < t)) {
        if (lane < 32)
          v = __hip_atomic_load(pollflag, __ATOMIC_RELAXED, __HIP_MEMORY_SCOPE_AGENT);
      }

      // ---- h loads (sc1 -> coherent LLC) + h-part MFMAs ----
      const u64* hp = (const u64*)(hbuf + (size_t)((t & 1) ^ 1) * BB * HH + hrow);
      h128 u0, u1, u2, u3;
      u0.q[0] = __hip_atomic_load(hp +  0, __ATOMIC_RELAXED, __HIP_MEMORY_SCOPE_AGENT);
      u0.q[1] = __hip_atomic_load(hp +  1, __ATOMIC_RELAXED, __HIP_MEMORY_SCOPE_AGENT);
      u1.q[0] = __hip_atomic_load(hp +  8, __ATOMIC_RELAXED, __HIP_MEMORY_SCOPE_AGENT);
      u1.q[1] = __hip_atomic_load(hp +  9, __ATOMIC_RELAXED, __HIP_MEMORY_SCOPE_AGENT);
      u2.q[0] = __hip_atomic_load(hp + 16, __ATOMIC_RELAXED, __HIP_MEMORY_SCOPE_AGENT);
      u2.q[1] = __hip_atomic_load(hp + 17, __ATOMIC_RELAXED, __HIP_MEMORY_SCOPE_AGENT);
      u3.q[0] = __hip_atomic_load(hp + 24, __ATOMIC_RELAXED, __HIP_MEMORY_SCOPE_AGENT);
      u3.q[1] = __hip_atomic_load(hp + 25, __ATOMIC_RELAXED, __HIP_MEMORY_SCOPE_AGENT);

#pragma unroll
      for (int g = 0; g < 4; ++g) {
        acc[g] = __builtin_amdgcn_mfma_f32_16x16x32_bf16(u0.v, wf[g][4], acc[g], 0, 0, 0);
        acc[g] = __builtin_amdgcn_mfma_f32_16x16x32_bf16(u1.v, wf[g][5], acc[g], 0, 0, 0);
        acc[g] = __builtin_amdgcn_mfma_f32_16x16x32_bf16(u2.v, wf[g][6], acc[g], 0, 0, 0);
        acc[g] = __builtin_amdgcn_mfma_f32_16x16x32_bf16(u3.v, wf[g][7], acc[g], 0, 0, 0);
      }
    }

    // ---- write K-partials to LDS (parity buffer) ----
    const int pb = t & 1;
#pragma unroll
    for (int g = 0; g < 4; ++g) part[pb][wave][g][lane] = acc[g];
    __syncthreads();

    // ---- per-thread reduce over 4 waves + gate nonlinearity ----
    float g0 = b0, g1 = b1, g2 = b2, g3 = b3;
#pragma unroll
    for (int w = 0; w < 4; ++w) {
      g0 += ((const float*)&part[pb][w][0][lsrc])[rsrc];
      g1 += ((const float*)&part[pb][w][1][lsrc])[rsrc];
      g2 += ((const float*)&part[pb][w][2][lsrc])[rsrc];
      g3 += ((const float*)&part[pb][w][3][lsrc])[rsrc];
    }
    float av = ftanh(g0);
    float iv = fsig(g1);
    float fv = fsig(g2);
    float ov = fsig(g3);
    s_c = av * iv + s_c * fv;
    float hv = ftanh(s_c) * ov;

    if (t < TT - 1) {
      // ---- publish h (pack 2 bf16 per u32, sc1 store) ----
      unsigned mybf = (unsigned)f2bf(hv);
      unsigned nxbf = (unsigned)__shfl_down((int)mybf, 1);
      if ((tid & 1) == 0) {
        unsigned pack = mybf | (nxbf << 16);
        unsigned* dst = (unsigned*)(hbuf + (size_t)pb * BB * HH + hstore_el);
        __hip_atomic_store(dst, pack, __ATOMIC_RELAXED, __HIP_MEMORY_SCOPE_AGENT);
      }
      // ---- drain all waves' h stores (compiler emits vmcnt(0) before s_barrier),
      //      then one plain flag store per block (no RMW) ----
      __syncthreads();
      if (tid == 0)
        __hip_atomic_store(myflag, (unsigned)(t + 1), __ATOMIC_RELAXED,
                           __HIP_MEMORY_SCOPE_AGENT);
    }

    // ---- out store AFTER flag publish (off the sync critical path) ----
    out[(size_t)t * BB * HH + hstore_el] = hv;
  }
}

extern "C" void kernel_launch(void* const* d_in, const int* in_sizes, int n_in,
                              void* d_out, int out_size, void* d_ws, size_t ws_size,
                              hipStream_t stream) {
  const float* X   = (const float*)d_in[0];
  const float* Wax = (const float*)d_in[1];
  const float* Wix = (const float*)d_in[2];
  const float* Wfx = (const float*)d_in[3];
  const float* Wox = (const float*)d_in[4];
  const float* Wah = (const float*)d_in[5];
  const float* Wih = (const float*)d_in[6];
  const float* Wfh = (const float*)d_in[7];
  const float* Woh = (const float*)d_in[8];
  const float* ba  = (const float*)d_in[9];
  const float* bi  = (const float*)d_in[10];
  const float* bf  = (const float*)d_in[11];
  const float* bo  = (const float*)d_in[12];
  float* out = (float*)d_out;

  char* ws = (char*)d_ws;
  unsigned short* Xbf  = (unsigned short*)ws;                            // 33,554,432 B
  unsigned short* WT   = (unsigned short*)(ws + 33554432);               //  4,194,304 B
  unsigned short* hbuf = (unsigned short*)(ws + 33554432 + 4194304);     //    524,288 B (2 planes)
  unsigned* flags      = (unsigned*)(ws + 33554432 + 4194304 + 524288);  //     32,768 B

  // only flags need zeroing (t=0 skips h-part; hbuf written before first read)
  hipMemsetAsync(flags, 0, 32768, stream);

  convert_x_kernel<<<8192, 256, 0, stream>>>(X, Xbf);
  build_wt_kernel<<<512, 256, 0, stream>>>(Wax, Wix, Wfx, Wox, Wah, Wih, Wfh, Woh, WT);
  lstm_main<<<NBLK, 256, 0, stream>>>(Xbf, WT, ba, bi, bf, bo, hbuf, out, flags);
}

// Round 7
// 795.306 us; speedup vs baseline: 1.7483x; 1.0443x over previous
//
#include <hip/hip_runtime.h>

// LSTM T=256, B=128, D=512, H=512 — round 7: XCD-local fast path, wait-free setup,
// out-mediated h exchange (per-step slots => staleness is harmless by determinism).
//   grid = 256 blocks x 256 threads (4 waves), 32KB LDS (co-residency shape = r3/r5).
//   Registration (tid0): claim (xcc+i)&7 counters until slot<32 (wait-free,
//   pigeonhole-guaranteed). Members publish XCD; group FAST iff uniform.
//   FAST: h via plain stores/loads through the group's own XCD L2.
//   SLOW: h via sc1 (LLC) — r5-proven, correct on any placement.
//   Flags: ALWAYS sc1 + memset per launch (ordering must be genuinely fresh).
//   Per-wave flags: own-wave vmcnt(0) drain, no block barriers on publish path.

#define TT 256
#define BB 128
#define DD 512
#define HH 512
#define KK 1024
#define NBLK 256

typedef __bf16 bf16x8 __attribute__((ext_vector_type(8)));
typedef float f32x4 __attribute__((ext_vector_type(4)));
typedef unsigned short u16x8 __attribute__((ext_vector_type(8)));
typedef unsigned long long u64;

__device__ __forceinline__ unsigned short f2bf(float f) {
  unsigned b = __builtin_bit_cast(unsigned, f);
  return (unsigned short)((b + 0x7fffu + ((b >> 16) & 1u)) >> 16);
}
__device__ __forceinline__ float fexp(float x) {
  return __builtin_amdgcn_exp2f(x * 1.4426950408889634f);
}
__device__ __forceinline__ float fsig(float x) {
  return __builtin_amdgcn_rcpf(1.0f + fexp(-x));
}
__device__ __forceinline__ float ftanh(float x) {
  return 2.0f * fsig(2.0f * x) - 1.0f;
}

// ---- prep: X fp32 -> bf16 (RNE), 8 elems/thread ----
__global__ __launch_bounds__(256) void convert_x_kernel(const float* __restrict__ X,
                                                        unsigned short* __restrict__ Xbf) {
  size_t i = (size_t)blockIdx.x * 256 + threadIdx.x;
  const float4* src = (const float4*)X + i * 2;
  float4 v0 = src[0], v1 = src[1];
  u16x8 o;
  o[0] = f2bf(v0.x); o[1] = f2bf(v0.y); o[2] = f2bf(v0.z); o[3] = f2bf(v0.w);
  o[4] = f2bf(v1.x); o[5] = f2bf(v1.y); o[6] = f2bf(v1.z); o[7] = f2bf(v1.w);
  ((u16x8*)Xbf)[i] = o;
}

// ---- prep: build WT[g][k] bf16, g = q*512 + j; k<512 from Wq_x[k][j], else Wq_h[k-512][j].
__global__ __launch_bounds__(256) void build_wt_kernel(
    const float* __restrict__ Wax, const float* __restrict__ Wix,
    const float* __restrict__ Wfx, const float* __restrict__ Wox,
    const float* __restrict__ Wah, const float* __restrict__ Wih,
    const float* __restrict__ Wfh, const float* __restrict__ Woh,
    unsigned short* __restrict__ WT) {
  __shared__ float tile[64][65];
  int bid = blockIdx.x;           // q*128 + jt*16 + kt
  int q  = bid >> 7;
  int jt = (bid >> 4) & 7;
  int kt = bid & 15;
  const float* Wx[4] = {Wax, Wix, Wfx, Wox};
  const float* Wh[4] = {Wah, Wih, Wfh, Woh};
  const float* src = (kt < 8) ? Wx[q] : Wh[q];
  int k0 = (kt & 7) * 64;
  int j0 = jt * 64;
  int tid = threadIdx.x;
#pragma unroll
  for (int e = 0; e < 16; ++e) {
    int lin = e * 256 + tid;
    int kk = lin >> 6, jj = lin & 63;
    tile[kk][jj] = src[(size_t)(k0 + kk) * HH + j0 + jj];
  }
  __syncthreads();
#pragma unroll
  for (int e = 0; e < 16; ++e) {
    int lin = e * 256 + tid;
    int jj = lin >> 6, kk = lin & 63;
    WT[(size_t)(q * HH + j0 + jj) * KK + kt * 64 + kk] = f2bf(tile[kk][jj]);
  }
}

// ---- recurrence body, templated on locality of the h path ----
template <bool LOC>
__device__ __forceinline__ void lstm_run(
    int tid, int rb, int cb,
    const unsigned short* __restrict__ Xbf,
    const unsigned short* __restrict__ WT,
    const float* __restrict__ ba, const float* __restrict__ bi,
    const float* __restrict__ bfg, const float* __restrict__ bo,
    float* __restrict__ out,
    unsigned* __restrict__ flags,        // [256 blocks][4 waves] x 32-u32 lines
    f32x4 (*part)[4][4][64]) {
  const int lane = tid & 63;
  const int wave = tid >> 6;
  const int l15 = lane & 15;
  const int lk8 = (lane >> 4) * 8;
  const int rbase = rb * 16;
  const int colg = cb * 16 + l15;
  const int wk = wave * 128;

  // ---- preload W fragments (constant across timesteps) ----
  bf16x8 wf[4][8];
#pragma unroll
  for (int g = 0; g < 4; ++g) {
    const unsigned short* wg = WT + (size_t)(g * HH + colg) * KK + lk8;
#pragma unroll
    for (int c = 0; c < 8; ++c) {
      int kb = (c < 4) ? (wk + c * 32) : (DD + wk + (c - 4) * 32);
      wf[g][c] = *(const bf16x8*)(wg + kb);
    }
  }

  const int el_row = tid >> 4;          // 0..15  (wave = el_row>>2)
  const int el_col = tid & 15;
  const int el_colg = cb * 16 + el_col;
  const int el_rowg = rbase + el_row;
  const float b0 = ba[el_colg], b1 = bi[el_colg], b2 = bfg[el_colg], b3 = bo[el_colg];
  const int lsrc = (el_row >> 2) * 16 + el_col;
  const int rsrc = el_row & 3;

  const unsigned short* xbase = Xbf + (size_t)(rbase + l15) * DD + wk + lk8;
  const size_t hread_off = (size_t)(rbase + l15) * HH + wk;   // + c*32 + lk8 later
  const size_t ostore_el = (size_t)el_rowg * HH + el_colg;

  unsigned* myflag = flags + (size_t)((rb * 32 + cb) * 4 + wave) * 32;
  // consumer wave needs producer blocks cb' = wave*8 .. wave*8+7, all 4 waves:
  const unsigned* pollf = flags +
      (size_t)((rb * 32 + (wave * 8 + ((lane & 31) >> 2))) * 4 + (lane & 3)) * 32;

  float s_c = 0.f;

  for (int t = 0; t < TT; ++t) {
    // ---- x part (no cross-block dependency) ----
    const unsigned short* xt = xbase + (size_t)t * BB * DD;
    bf16x8 ax0 = *(const bf16x8*)(xt);
    bf16x8 ax1 = *(const bf16x8*)(xt + 32);
    bf16x8 ax2 = *(const bf16x8*)(xt + 64);
    bf16x8 ax3 = *(const bf16x8*)(xt + 96);

    f32x4 acc[4];
#pragma unroll
    for (int g = 0; g < 4; ++g) {
      f32x4 z = {0.f, 0.f, 0.f, 0.f};
      acc[g] = __builtin_amdgcn_mfma_f32_16x16x32_bf16(ax0, wf[g][0], z, 0, 0, 0);
      acc[g] = __builtin_amdgcn_mfma_f32_16x16x32_bf16(ax1, wf[g][1], acc[g], 0, 0, 0);
      acc[g] = __builtin_amdgcn_mfma_f32_16x16x32_bf16(ax2, wf[g][2], acc[g], 0, 0, 0);
      acc[g] = __builtin_amdgcn_mfma_f32_16x16x32_bf16(ax3, wf[g][3], acc[g], 0, 0, 0);
    }

    if (t > 0) {
      // ---- poll 32 per-wave flags (lanes 0..31), sc1 = genuinely fresh ----
      unsigned v = (unsigned)t;
      if (lane < 32)
        v = __hip_atomic_load(pollf, __ATOMIC_RELAXED, __HIP_MEMORY_SCOPE_AGENT);
      while (__any((int)v < t)) {
        __builtin_amdgcn_s_sleep(1);
        if (lane < 32)
          v = __hip_atomic_load(pollf, __ATOMIC_RELAXED, __HIP_MEMORY_SCOPE_AGENT);
      }
      asm volatile("" ::: "memory");  // keep h loads below the poll

      // ---- h loads from out[t-1] (f32) -> bf16 fragments ----
      const float* hsrc = out + (size_t)(t - 1) * BB * HH + hread_off;
      bf16x8 hf[4];
#pragma unroll
      for (int c = 0; c < 4; ++c) {
        float hv8[8];
        if constexpr (LOC) {
          float4 a = *(const float4*)(hsrc + c * 32 + lk8);
          float4 b = *(const float4*)(hsrc + c * 32 + lk8 + 4);
          hv8[0] = a.x; hv8[1] = a.y; hv8[2] = a.z; hv8[3] = a.w;
          hv8[4] = b.x; hv8[5] = b.y; hv8[6] = b.z; hv8[7] = b.w;
        } else {
          const u64* hq = (const u64*)(hsrc + c * 32 + lk8);
#pragma unroll
          for (int j = 0; j < 4; ++j) {
            u64 q = __hip_atomic_load(hq + j, __ATOMIC_RELAXED, __HIP_MEMORY_SCOPE_AGENT);
            hv8[2 * j]     = __builtin_bit_cast(float, (unsigned)(q & 0xffffffffu));
            hv8[2 * j + 1] = __builtin_bit_cast(float, (unsigned)(q >> 32));
          }
        }
        u16x8 hb;
#pragma unroll
        for (int j = 0; j < 8; ++j) hb[j] = f2bf(hv8[j]);
        hf[c] = __builtin_bit_cast(bf16x8, hb);
      }

#pragma unroll
      for (int g = 0; g < 4; ++g) {
        acc[g] = __builtin_amdgcn_mfma_f32_16x16x32_bf16(hf[0], wf[g][4], acc[g], 0, 0, 0);
        acc[g] = __builtin_amdgcn_mfma_f32_16x16x32_bf16(hf[1], wf[g][5], acc[g], 0, 0, 0);
        acc[g] = __builtin_amdgcn_mfma_f32_16x16x32_bf16(hf[2], wf[g][6], acc[g], 0, 0, 0);
        acc[g] = __builtin_amdgcn_mfma_f32_16x16x32_bf16(hf[3], wf[g][7], acc[g], 0, 0, 0);
      }
    }

    // ---- K-partials to LDS (parity double-buffer) ----
    const int pb = t & 1;
#pragma unroll
    for (int g = 0; g < 4; ++g) part[pb][wave][g][lane] = acc[g];
    __syncthreads();

    // ---- reduce over 4 waves + gates (1 element/thread) ----
    float g0 = b0, g1 = b1, g2 = b2, g3 = b3;
#pragma unroll
    for (int w = 0; w < 4; ++w) {
      g0 += ((const float*)&part[pb][w][0][lsrc])[rsrc];
      g1 += ((const float*)&part[pb][w][1][lsrc])[rsrc];
      g2 += ((const float*)&part[pb][w][2][lsrc])[rsrc];
      g3 += ((const float*)&part[pb][w][3][lsrc])[rsrc];
    }
    float av = ftanh(g0);
    float iv = fsig(g1);
    float fv = fsig(g2);
    float ov = fsig(g3);
    s_c = av * iv + s_c * fv;
    float hv = ftanh(s_c) * ov;

    // ---- publish h_t via out[t] (the exchange medium) ----
    float* odst = out + (size_t)t * BB * HH + ostore_el;
    if constexpr (LOC) {
      *odst = hv;                                   // plain -> local XCD L2
    } else {
      __hip_atomic_store((unsigned*)odst, __builtin_bit_cast(unsigned, hv),
                         __ATOMIC_RELAXED, __HIP_MEMORY_SCOPE_AGENT);
    }

    if (t < TT - 1) {
      // own-wave drain (covers this wave's 64 out-stores), then per-wave flag
      asm volatile("s_waitcnt vmcnt(0)" ::: "memory");
      if (lane == 0)
        __hip_atomic_store(myflag, (unsigned)(t + 1), __ATOMIC_RELAXED,
                           __HIP_MEMORY_SCOPE_AGENT);
    }

    // keep h-part W fragments register-resident across iterations
#pragma unroll
    for (int g = 0; g < 4; ++g)
#pragma unroll
      for (int c = 4; c < 8; ++c)
        asm volatile("" : "+v"(wf[g][c]));
  }
}

// ---- main persistent kernel: wait-free XCD claim, uniformity check, run ----
__global__ __launch_bounds__(256, 1) void lstm_main(
    const unsigned short* __restrict__ Xbf,
    const unsigned short* __restrict__ WT,
    const float* __restrict__ ba, const float* __restrict__ bi,
    const float* __restrict__ bfg, const float* __restrict__ bo,
    float* __restrict__ out,
    unsigned* __restrict__ flags,
    unsigned* __restrict__ regcnt,   // [8] x 32-u32 pad
    unsigned* __restrict__ gxcd) {   // [8][32] u32 (xcc+1 of each member)
  __shared__ f32x4 part[2][4][4][64];   // 32KB — same residency shape as r3/r5
  __shared__ unsigned s_meta[4];

  const int tid = threadIdx.x;
  if (tid == 0) {
    unsigned xcc;
    asm volatile("s_getreg_b32 %0, hwreg(HW_REG_XCC_ID, 0, 32)" : "=s"(xcc));
    xcc &= 7u;
    // wait-free claim: try own XCD's group first, then others; pigeonhole
    // guarantees one of the 8 fetch_adds returns slot < 32.
    unsigned grp = 0, slot = 0;
#pragma unroll
    for (int i = 0; i < 8; ++i) {
      unsigned x = (xcc + (unsigned)i) & 7u;
      unsigned s = __hip_atomic_fetch_add(&regcnt[x * 32], 1u,
                                          __ATOMIC_RELAXED, __HIP_MEMORY_SCOPE_AGENT);
      if (s < 32u) { grp = x; slot = s; break; }
    }
    // publish membership, then wait for the 31 peers (all blocks are resident:
    // claiming is wait-free, so every block reaches this point)
    __hip_atomic_store(&gxcd[grp * 32 + slot], xcc + 1u,
                       __ATOMIC_RELAXED, __HIP_MEMORY_SCOPE_AGENT);
    unsigned uok;
    while (true) {
      bool all = true; uok = 1u;
      for (int i = 0; i < 32; ++i) {
        unsigned e = __hip_atomic_load(&gxcd[grp * 32 + i], __ATOMIC_RELAXED,
                                       __HIP_MEMORY_SCOPE_AGENT);
        if (e == 0u) { all = false; break; }
        if (e != grp + 1u) uok = 0u;
      }
      if (all) break;
      __builtin_amdgcn_s_sleep(8);
    }
    s_meta[0] = grp; s_meta[1] = slot; s_meta[2] = uok;
  }
  __syncthreads();
  const int rb = (int)s_meta[0];
  const int cb = (int)s_meta[1];
  if (s_meta[2]) {
    lstm_run<true>(tid, rb, cb, Xbf, WT, ba, bi, bfg, bo, out, flags, part);
  } else {
    lstm_run<false>(tid, rb, cb, Xbf, WT, ba, bi, bfg, bo, out, flags, part);
  }
}

extern "C" void kernel_launch(void* const* d_in, const int* in_sizes, int n_in,
                              void* d_out, int out_size, void* d_ws, size_t ws_size,
                              hipStream_t stream) {
  const float* X   = (const float*)d_in[0];
  const float* Wax = (const float*)d_in[1];
  const float* Wix = (const float*)d_in[2];
  const float* Wfx = (const float*)d_in[3];
  const float* Wox = (const float*)d_in[4];
  const float* Wah = (const float*)d_in[5];
  const float* Wih = (const float*)d_in[6];
  const float* Wfh = (const float*)d_in[7];
  const float* Woh = (const float*)d_in[8];
  const float* ba  = (const float*)d_in[9];
  const float* bi  = (const float*)d_in[10];
  const float* bf  = (const float*)d_in[11];
  const float* bo  = (const float*)d_in[12];
  float* out = (float*)d_out;

  char* ws = (char*)d_ws;
  unsigned short* Xbf = (unsigned short*)ws;                        // 33,554,432 B
  unsigned short* WT  = (unsigned short*)(ws + 33554432);           //  4,194,304 B
  char* syncbase = ws + 33554432 + 4194304;
  unsigned* flags  = (unsigned*)syncbase;                           //    131,072 B
  unsigned* regcnt = (unsigned*)(syncbase + 131072);                //      1,024 B
  unsigned* gxcd   = (unsigned*)(syncbase + 131072 + 1024);         //      1,024 B

  // zero flags + registration state every launch (replay safety; flags are the
  // only sync data that must be genuinely fresh — h staleness is benign since
  // per-step h values are replay-deterministic)
  hipMemsetAsync(syncbase, 0, 131072 + 1024 + 1024, stream);

  convert_x_kernel<<<8192, 256, 0, stream>>>(X, Xbf);
  build_wt_kernel<<<512, 256, 0, stream>>>(Wax, Wix, Wfx, Wox, Wah, Wih, Wfh, Woh, WT);
  lstm_main<<<NBLK, 256, 0, stream>>>(Xbf, WT, ba, bi, bf, bo, out,
                                      flags, regcnt, gxcd);
}